// Round 1
// baseline (15593.694 us; speedup 1.0000x reference)
//
#include <hip/hip_runtime.h>

#define BB 64
#define NN 1000
#define FF 12
#define EE 64
#define HH 128
#define OO 16
#define GG 512

__device__ __forceinline__ float rcp_(float x){ return __builtin_amdgcn_rcpf(x); }
__device__ __forceinline__ float sigm_(float x){ return rcp_(1.0f + __expf(-x)); }
// exact algebraic form of tanh: (e^{2x}-1)/(e^{2x}+1) = 1 - 2/(e^{2x}+1)
__device__ __forceinline__ float tanh_(float x){ return 1.0f - 2.0f*rcp_(__expf(2.0f*x) + 1.0f); }

__global__ __launch_bounds__(512, 2)
void decoder_kernel(const float* __restrict__ enc,   // (B,1,N,E)
                    const float* __restrict__ mean,  // (B,FUT,N,O)
                    const float* __restrict__ sv,    // (1,O)
                    const float* __restrict__ h0,    // (2,O)
                    const float* __restrict__ c0,    // (2,H)
                    const float* __restrict__ Wih0,  // (G, E+O)
                    const float* __restrict__ Whh0,  // (G, O)
                    const float* __restrict__ bih0,  // (G)
                    const float* __restrict__ bhh0,  // (G)
                    const float* __restrict__ Whr0,  // (O, H)
                    const float* __restrict__ Wih1,  // (G, O)
                    const float* __restrict__ Whh1,  // (G, O)
                    const float* __restrict__ bih1,  // (G)
                    const float* __restrict__ bhh1,  // (G)
                    const float* __restrict__ Whr1,  // (O, H)
                    float* __restrict__ out)         // (B,FUT,N,O)
{
    const int t = threadIdx.x;   // gate index for both layers
    const int b = blockIdx.x;    // batch chain

    __shared__ float s_last[OO];
    __shared__ float s_h1[OO];
    __shared__ float s_h2[OO];
    __shared__ float s_gates[GG];
    __shared__ float s_hfull[HH];
    __shared__ float s_enc[EE];
    __shared__ float s_nm[OO];

    // ---- per-thread weights in registers ----
    float w_enc[EE];                       // W_ih0[t, 0:64]  (enc part, used once/node)
    float w_loop[OO], w_hh0[OO], w_ih1[OO], w_hh1[OO];
    {
        const float* r = Wih0 + t*(EE+OO);
        #pragma unroll
        for (int e=0;e<EE;e++) w_enc[e] = r[e];
        #pragma unroll
        for (int j=0;j<OO;j++) w_loop[j] = r[EE+j];
        #pragma unroll
        for (int j=0;j<OO;j++) w_hh0[j] = Whh0[t*OO+j];
        #pragma unroll
        for (int j=0;j<OO;j++) w_ih1[j] = Wih1[t*OO+j];
        #pragma unroll
        for (int j=0;j<OO;j++) w_hh1[j] = Whh1[t*OO+j];
    }
    const float bias0 = bih0[t] + bhh0[t];
    const float bias1 = bih1[t] + bhh1[t];

    // projection assignment: output j16 = t>>5, k-chunk kb = (t&31)*4
    const int j16 = t >> 5;
    const int kb  = (t & 31) * 4;
    float wp0[4], wp1[4];
    #pragma unroll
    for (int u=0;u<4;u++){
        wp0[u] = Whr0[j16*HH + kb + u];
        wp1[u] = Whr1[j16*HH + kb + u];
    }

    // cell state lives in the registers of threads 0..127
    float c1 = (t < HH) ? c0[t]      : 0.0f;
    float c2 = (t < HH) ? c0[HH + t] : 0.0f;
    if (t < OO){
        s_last[t] = sv[t];        // last0 = s[0]
        s_h1[t]   = h0[t];        // h_0[0]
        s_h2[t]   = h0[OO + t];   // h_0[1]
    }
    __syncthreads();

    const float* encB  = enc  + (size_t)b * NN * EE;
    const float* meanB = mean + (size_t)b * FF * NN * OO;
    float*       outB  = out  + (size_t)b * FF * NN * OO;

    const bool isTanhGate = ((t >> 7) == 2);   // gates[256:384] are 'g' -> tanh

    for (int n = 0; n < NN; ++n){
        // ---- per-node loads: enc_t and node_mean ----
        if (t < EE){
            s_enc[t] = encB[n*EE + t];
        } else if (t < EE + OO){
            const int j = t - EE;
            float a = 0.0f;
            #pragma unroll
            for (int f=0; f<FF; ++f) a += meanB[(f*NN + n)*OO + j];
            s_nm[j] = a * (1.0f/12.0f);
        }
        __syncthreads();

        // per-node constant part of layer-0 gate t
        float pre0 = bias0;
        #pragma unroll
        for (int e=0;e<EE;e++) pre0 += s_enc[e]*w_enc[e];
        #pragma unroll
        for (int j=0;j<OO;j++) pre0 += s_nm[j]*w_loop[j];

        for (int f=0; f<FF; ++f){
            // ---- layer 0 gates (K=16 + K=16) ----
            float acc = pre0;
            #pragma unroll
            for (int j=0;j<OO;j++) acc += s_last[j]*w_loop[j];
            #pragma unroll
            for (int j=0;j<OO;j++) acc += s_h1[j]*w_hh0[j];
            s_gates[t] = isTanhGate ? tanh_(acc) : sigm_(acc);
            __syncthreads();                                   // B1

            // ---- layer 0 cell (threads 0..127) ----
            if (t < HH){
                float iv = s_gates[t],      fv = s_gates[HH + t];
                float gv = s_gates[2*HH+t], ov = s_gates[3*HH + t];
                c1 = fv*c1 + iv*gv;
                s_hfull[t] = ov * tanh_(c1);
            }
            __syncthreads();                                   // B2

            // ---- layer 0 projection: h1_new[j] = sum_k hfull[k]*Whr0[j,k] ----
            {
                float p = s_hfull[kb+0]*wp0[0] + s_hfull[kb+1]*wp0[1]
                        + s_hfull[kb+2]*wp0[2] + s_hfull[kb+3]*wp0[3];
                p += __shfl_down(p, 16, 32);
                p += __shfl_down(p,  8, 32);
                p += __shfl_down(p,  4, 32);
                p += __shfl_down(p,  2, 32);
                p += __shfl_down(p,  1, 32);
                if ((t & 31) == 0) s_h1[j16] = p;
            }
            __syncthreads();                                   // B3

            // ---- layer 1 gates (K=16 + K=16) ----
            float acc1 = bias1;
            #pragma unroll
            for (int j=0;j<OO;j++) acc1 += s_h1[j]*w_ih1[j];
            #pragma unroll
            for (int j=0;j<OO;j++) acc1 += s_h2[j]*w_hh1[j];
            s_gates[t] = isTanhGate ? tanh_(acc1) : sigm_(acc1);
            __syncthreads();                                   // B4

            // ---- layer 1 cell ----
            if (t < HH){
                float iv = s_gates[t],      fv = s_gates[HH + t];
                float gv = s_gates[2*HH+t], ov = s_gates[3*HH + t];
                c2 = fv*c2 + iv*gv;
                s_hfull[t] = ov * tanh_(c2);
            }
            __syncthreads();                                   // B5

            // ---- layer 1 projection + output ----
            {
                float p = s_hfull[kb+0]*wp1[0] + s_hfull[kb+1]*wp1[1]
                        + s_hfull[kb+2]*wp1[2] + s_hfull[kb+3]*wp1[3];
                p += __shfl_down(p, 16, 32);
                p += __shfl_down(p,  8, 32);
                p += __shfl_down(p,  4, 32);
                p += __shfl_down(p,  2, 32);
                p += __shfl_down(p,  1, 32);
                if ((t & 31) == 0){
                    s_h2[j16]   = p;     // new h2
                    s_last[j16] = p;     // new 'last'
                    outB[(f*NN + n)*OO + j16] = p + s_nm[j16];
                }
            }
            __syncthreads();                                   // B6
        }
    }
}

extern "C" void kernel_launch(void* const* d_in, const int* in_sizes, int n_in,
                              void* d_out, int out_size, void* d_ws, size_t ws_size,
                              hipStream_t stream) {
    const float* enc  = (const float*)d_in[0];
    const float* mean = (const float*)d_in[1];
    const float* sv   = (const float*)d_in[2];
    const float* h0   = (const float*)d_in[3];
    const float* c0   = (const float*)d_in[4];
    const float* Wih0 = (const float*)d_in[5];
    const float* Whh0 = (const float*)d_in[6];
    const float* bih0 = (const float*)d_in[7];
    const float* bhh0 = (const float*)d_in[8];
    const float* Whr0 = (const float*)d_in[9];
    const float* Wih1 = (const float*)d_in[10];
    const float* Whh1 = (const float*)d_in[11];
    const float* bih1 = (const float*)d_in[12];
    const float* bhh1 = (const float*)d_in[13];
    const float* Whr1 = (const float*)d_in[14];
    float* out = (float*)d_out;

    decoder_kernel<<<dim3(BB), dim3(512), 0, stream>>>(
        enc, mean, sv, h0, c0,
        Wih0, Whh0, bih0, bhh0, Whr0,
        Wih1, Whh1, bih1, bhh1, Whr1,
        out);
}